// Round 1
// 92.037 us; speedup vs baseline: 1.0146x; 1.0146x over previous
//
#include <hip/hip_runtime.h>
#include <hip/hip_fp16.h>

#define B_ 4
#define H_ 128
#define W_ 128
#define HW_ 16384

typedef _Float16 half8 __attribute__((ext_vector_type(8)));
typedef float floatx16 __attribute__((ext_vector_type(16)));
typedef __attribute__((address_space(3))) void lds_void;
typedef const __attribute__((address_space(1))) void gbl_void;

// ws layout (bytes):
//   W2L : f16 [9 tap][4 ks][2 og][64 lane][8] = 73,728  at offset 0
//   W0L : f16 [9 tap][4 ks][64 lane][8]       = 36,864  at offset 73,728
//   xh  : f16 [4 b][8 ch-octet][16384 pix][8] = 8,388,608 at offset 110,592
// total 8,499,200 B (<< 256 MiB ws)

// ---------------- prep: weight swizzles + x f32->f16 chunk-transpose ----------------
// blocks [0,2048): x -> xh   (thread = one (b,ch-octet,pixel), 8 strided reads, 16B write)
// blocks [2048,2264): weight swizzles for 32x32x16 B-fragments (unchanged from prev)
__global__ __launch_bounds__(256) void k_prep(
    const float* __restrict__ x, const float* __restrict__ w_dcn,
    const float* __restrict__ w_off,
    __half* __restrict__ W2L, __half* __restrict__ W0L,
    _Float16* __restrict__ xh)
{
    int bid = blockIdx.x;
    int t = threadIdx.x;
    if (bid < 2048) {
        int idx = bid*256 + t;               // 524,288 = 4b x 8oct x 16384pix
        int p  = idx & (HW_-1);
        int bc = idx >> 14;                  // b*8 + ch-octet
        const float* s = x + (size_t)bc*8*HW_ + p;
        half8 vv;
        #pragma unroll
        for (int e = 0; e < 8; ++e) vv[e] = (_Float16)s[e*HW_];
        *(half8*)(xh + (size_t)idx*8) = vv;
    } else {
        int idx = (bid - 2048)*256 + t;      // 55,296 threads
        if (idx < 36864) {
            int e = idx & 7, lane = (idx>>3) & 63, og = (idx>>9) & 1;
            int ks = (idx>>10) & 3, tap = idx >> 12;
            int o = og*32 + (lane & 31);
            int c = ks*16 + (lane >> 5)*8 + e;
            W2L[idx] = __float2half(w_dcn[o*576 + c*9 + tap]);
        } else {
            int i2 = idx - 36864;
            int e = i2 & 7, lane = (i2>>3) & 63;
            int ks = (i2>>9) & 3, tap = i2 >> 11;
            int oc = lane & 31;
            int c = ks*16 + (lane >> 5)*8 + e;
            W0L[i2] = (oc < 18) ? __float2half(w_off[oc*576 + c*9 + tap])
                                : __float2half(0.f);
        }
    }
}

// ---------------- fused kernel ----------------
// block = 128 thr = 2 waves; 64-position tile (2 rows x 32 cols). Wave v owns
// row v: 32 positions x ALL 64 o via two 32x32x16 D-tiles.
// A-frag: m = lane&31 (=pos col), k = (lane>>5)*8+e. C/D: col=lane&31 (=o),
// row = (reg&3)+8*(reg>>2)+4*(lane>>5) (=pos col).
// LDS = 36,864 B -> 4 blocks/CU (8 waves):
//   haloT : [8 chunk][216 pix(6r x 36c)][16B] FLAT CONTIGUOUS (chunk stride
//           3456 B, no pad) -- required: global_load_lds writes base+lane*16
//           linearly, so the whole halo is one [1728][16B] array staged by
//           27 x global_load_lds_dwordx4 (per-lane global addr does the clamp)
//   wave region[v] (4,608 B): offL[32 pos][18 f32] (2,304 B) then overwritten
//     in-wave by desc[9 tap][32 pos][16 B] (same-wave DS ops in-order)
//   epilogue E[64][66] f32 (16,896 B) aliases haloT after final barrier
#define CHS2 3456
#define WLOC_OFF 27648
#define SMEM_SZ 36864

__global__ __launch_bounds__(128, 2) void k_fused(
    const float* __restrict__ x, const _Float16* __restrict__ xh,
    const _Float16* __restrict__ W2L, const _Float16* __restrict__ W0L,
    const float* __restrict__ b_off, const float* __restrict__ b_dcn,
    float* __restrict__ out)
{
    __shared__ __attribute__((aligned(16))) char smem[SMEM_SZ];
    char* halo_c = smem;

    int t = threadIdx.x;
    int lane = t & 63;
    int v = __builtin_amdgcn_readfirstlane(t >> 6);   // wave id 0/1 = tile row
    int c31 = lane & 31;                              // pos col / o col / oc
    int h8  = lane >> 5;                              // k-octet half

    char*  wl   = smem + WLOC_OFF + v*4608;
    float* offL = (float*)wl;                         // [32 pos][18] f32
    char*  desc = wl;                                 // [9 tap][32 pos][16 B]

    // XCD swizzle: contiguous half-image (one batch half) per XCD
    int bid  = blockIdx.x;
    int xcd  = bid & 7, sidx = bid >> 3;
    int orig = xcd*128 + sidx;
    int b    = orig >> 8;
    int rem  = orig & 255;
    int i0   = (rem >> 2) * 2;     // row-pair base
    int j0   = (rem & 3) * 32;     // col base

    const float* xf = x + (size_t)b * (64*HW_);

    // ---------- stage 6-row x 36-col halo via async global_load_lds (f16 src) ----------
    // 1728 16B-tasks = 27 full-wave instrs; wave0 issues i=0..13, wave1 i=14..26.
    // Per-lane SOURCE address carries the row/col clamp; LDS dest is linear.
    {
        int nst  = 14 - v;
        int base = v * 14;
        const _Float16* xhb = xh + ((size_t)b << 20);   // b * 8oct*16384*8
        for (int s = 0; s < nst; ++s) {
            int i   = base + s;
            int idx = (i << 6) + lane;                  // 0..1727
            int ch  = idx / 216;
            int pl  = idx - ch*216;
            int hr  = pl / 36;
            int hx  = pl - hr*36;
            int grow = min(max(i0 - 2 + hr, 0), H_-1);
            int gcol = min(max(j0 - 2 + hx, 0), W_-1);
            const _Float16* g = xhb + ((size_t)ch << 17) + (size_t)(((grow<<7) + gcol) << 3);
            __builtin_amdgcn_global_load_lds((gbl_void*)g,
                                             (lds_void*)(halo_c + (i << 10)),
                                             16, 0, 0);
        }
    }
    __syncthreads();   // barrier 1 of 3 (drains vmcnt)

    // ================= Phase A: offset conv (one 32x32 D-tile, oc<=18 used) =========
    floatx16 accA = {0.f,0.f,0.f,0.f,0.f,0.f,0.f,0.f,0.f,0.f,0.f,0.f,0.f,0.f,0.f,0.f};
    const half8 hz = {0,0,0,0,0,0,0,0};
    #pragma unroll
    for (int tap = 0; tap < 9; ++tap) {
        int kh = tap/3, kw = tap - (tap/3)*3;
        int ii = i0 + v - 1 + kh;
        int jj = j0 + c31 - 1 + kw;
        bool valid = (ii >= 0) && (ii < H_) && (jj >= 0) && (jj < W_);
        int pixA = (v + 1 + kh)*36 + (c31 + 1 + kw);
        #pragma unroll
        for (int s = 0; s < 4; ++s) {
            half8 a = *(const half8*)(halo_c + (s*2 + h8)*CHS2 + pixA*16);
            a = valid ? a : hz;
            half8 bf = *(const half8*)(W0L + ((tap*4+s)<<9) + (lane<<3));
            accA = __builtin_amdgcn_mfma_f32_32x32x16_f16(a, bf, accA, 0, 0, 0);
        }
    }
    // epilogue A (wave-local): col=c31 (=oc), row=(r&3)+8*(r>>2)+4*h8 (=local pos)
    {
        int oc = c31;
        if (oc < 18) {
            float bo = b_off[oc];
            #pragma unroll
            for (int r = 0; r < 16; ++r) {
                int row = (r & 3) + 8*(r >> 2) + 4*h8;
                offL[row*18 + oc] = accA[r] + bo;
            }
        }
    }
    // NO barrier: offL -> desc -> Phase-B is wave-local (in-order DS ops).

    // ======== descriptor build (wave-local): reads reg-staged, then stores ========
    float2 o2r[5];
    #pragma unroll
    for (int e = 0; e < 5; ++e) {
        int idx = e*64 + lane;                  // 288 descs: 32 pos x 9 taps
        if (idx < 288) {
            int pl = idx / 9, tap = idx - pl*9;
            o2r[e] = *(const float2*)(offL + pl*18 + 2*tap);
        }
    }
    uint4 dreg[5];
    #pragma unroll
    for (int e = 0; e < 5; ++e) {
        int idx = e*64 + lane;
        if (idx < 288) {
            int pl = idx / 9, tap = idx - pl*9;
            int kh = tap/3, kw = tap - (tap/3)*3;
            float py = (float)(i0 + v - 1 + kh) + o2r[e].x;
            float px = (float)(j0 + pl - 1 + kw) + o2r[e].y;
            float y0f = floorf(py), x0f = floorf(px);
            float dy = py - y0f, dx = px - x0f;
            int y0 = (int)y0f, x0i = (int)x0f;
            int y1 = y0 + 1,  x1 = x0i + 1;
            bool vy0 = (y0>=0)&(y0<H_),   vy1 = (y1>=0)&(y1<H_);
            bool vx0 = (x0i>=0)&(x0i<W_), vx1 = (x1>=0)&(x1<W_);
            int yc0 = min(max(y0,0),H_-1),  yc1 = min(max(y1,0),H_-1);
            int xc0 = min(max(x0i,0),W_-1), xc1 = min(max(x1,0),W_-1);
            float w00 = (1.f-dy)*(1.f-dx) * ((vy0&&vx0)?1.f:0.f);
            float w01 = (1.f-dy)*dx       * ((vy0&&vx1)?1.f:0.f);
            float w10 = dy*(1.f-dx)       * ((vy1&&vx0)?1.f:0.f);
            float w11 = dy*dx             * ((vy1&&vx1)?1.f:0.f);
            int hy0 = yc0 - (i0-2), hy1 = yc1 - (i0-2);
            int hx0 = xc0 - (j0-2), hx1 = xc1 - (j0-2);
            bool inh = ((unsigned)hy0 < 6u) & ((unsigned)hy1 < 6u)
                     & ((unsigned)hx0 < 36u) & ((unsigned)hx1 < 36u);
            unsigned a0,a1,a2,a3;
            if (inh) { a0 = hy0*36+hx0; a1 = hy0*36+hx1; a2 = hy1*36+hx0; a3 = hy1*36+hx1; }
            else     { a0 = ((yc0<<7)+xc0) | 0x8000u; a1 = (yc0<<7)+xc1;
                       a2 = (yc1<<7)+xc0;             a3 = (yc1<<7)+xc1; }
            __half2 hw0 = __floats2half2_rn(w00, w01);
            __half2 hw1 = __floats2half2_rn(w10, w11);
            dreg[e].x = a0 | (a1 << 16);
            dreg[e].y = a2 | (a3 << 16);
            dreg[e].z = *(unsigned*)&hw0;
            dreg[e].w = *(unsigned*)&hw1;
        }
    }
    #pragma unroll
    for (int e = 0; e < 5; ++e) {
        int idx = e*64 + lane;
        if (idx < 288) {
            int pl = idx / 9, tap = idx - pl*9;
            *(uint4*)(desc + (tap*32 + pl)*16) = dreg[e];   // [tap][pos] layout
        }
    }
    // NO barrier: Phase B reads only this wave's desc.

    // ================= Phase B: own-pos sample + 32x32x16 MFMA =================
    floatx16 acc0 = {0.f,0.f,0.f,0.f,0.f,0.f,0.f,0.f,0.f,0.f,0.f,0.f,0.f,0.f,0.f,0.f};
    floatx16 acc1 = acc0;

    const char* hqs0 = halo_c + (0*2 + h8)*CHS2;
    const char* hqs1 = halo_c + (1*2 + h8)*CHS2;
    const char* hqs2 = halo_c + (2*2 + h8)*CHS2;
    const char* hqs3 = halo_c + (3*2 + h8)*CHS2;

    #pragma unroll 3
    for (int tap = 0; tap < 9; ++tap) {
        uint4 d = *(const uint4*)(desc + (tap*32 + c31)*16);   // lanes l,l+32 same addr
        unsigned p0i = d.x & 0x7fffu, p1i = d.x >> 16;
        unsigned p2i = d.y & 0xffffu, p3i = d.y >> 16;
        bool inh = (d.x & 0x8000u) == 0u;
        unsigned short b00 = (unsigned short)(d.z & 0xffffu);
        unsigned short b01 = (unsigned short)(d.z >> 16);
        unsigned short b10 = (unsigned short)(d.w & 0xffffu);
        unsigned short b11 = (unsigned short)(d.w >> 16);
        _Float16 h00 = *(_Float16*)&b00, h01 = *(_Float16*)&b01;
        _Float16 h10 = *(_Float16*)&b10, h11 = *(_Float16*)&b11;
        half8 W00 = {h00,h00,h00,h00,h00,h00,h00,h00};
        half8 W01 = {h01,h01,h01,h01,h01,h01,h01,h01};
        half8 W10 = {h10,h10,h10,h10,h10,h10,h10,h10};
        half8 W11 = {h11,h11,h11,h11,h11,h11,h11,h11};
        half8 sk[4];
        const char* hb[4] = {hqs0, hqs1, hqs2, hqs3};
        #pragma unroll
        for (int s = 0; s < 4; ++s) {
            half8 v00, v01, v10, v11;
            if (inh) {
                v00 = *(const half8*)(hb[s] + p0i*16);
                v01 = *(const half8*)(hb[s] + p1i*16);
                v10 = *(const half8*)(hb[s] + p2i*16);
                v11 = *(const half8*)(hb[s] + p3i*16);
            } else {
                int chb = (s*2 + h8)*8;
                #pragma unroll
                for (int e = 0; e < 8; ++e) {
                    v00[e] = (_Float16)xf[(chb+e)*HW_ + (int)p0i];
                    v01[e] = (_Float16)xf[(chb+e)*HW_ + (int)p1i];
                    v10[e] = (_Float16)xf[(chb+e)*HW_ + (int)p2i];
                    v11[e] = (_Float16)xf[(chb+e)*HW_ + (int)p3i];
                }
            }
            sk[s] = v00*W00 + v01*W01 + v10*W10 + v11*W11;
        }
        #pragma unroll
        for (int s = 0; s < 4; ++s) {
            half8 bf0 = *(const half8*)(W2L + (((tap*4+s)*2+0)<<9) + (lane<<3));
            acc0 = __builtin_amdgcn_mfma_f32_32x32x16_f16(sk[s], bf0, acc0, 0, 0, 0);
            half8 bf1 = *(const half8*)(W2L + (((tap*4+s)*2+1)<<9) + (lane<<3));
            acc1 = __builtin_amdgcn_mfma_f32_32x32x16_f16(sk[s], bf1, acc1, 0, 0, 0);
        }
    }
    __syncthreads();   // barrier 2 of 3: halo dead; E aliases it

    // epilogue: E[64 pos][66]; D col=c31 -> o=og*32+c31, row -> pos=v*32+row
    float* E = (float*)smem;
    #pragma unroll
    for (int r = 0; r < 16; ++r) {
        int row = (r & 3) + 8*(r >> 2) + 4*h8;
        int pl  = v*32 + row;
        E[pl*66 + c31]      = acc0[r];
        E[pl*66 + 32 + c31] = acc1[r];
    }
    __syncthreads();   // barrier 3 of 3
    int obase = (b*64)*HW_ + i0*W_ + j0;
    int prow = (lane >> 5)*W_ + c31;
    #pragma unroll
    for (int rep = 0; rep < 32; ++rep) {
        int o = rep*2 + v;
        out[obase + o*HW_ + prow] = E[lane*66 + o] + b_dcn[o];
    }
}

extern "C" void kernel_launch(void* const* d_in, const int* in_sizes, int n_in,
                              void* d_out, int out_size, void* d_ws, size_t ws_size,
                              hipStream_t stream) {
    const float* x     = (const float*)d_in[0];
    const float* w_off = (const float*)d_in[1];
    const float* b_off = (const float*)d_in[2];
    const float* w_dcn = (const float*)d_in[3];
    const float* b_dcn = (const float*)d_in[4];
    float* out = (float*)d_out;

    __half* W2L = (__half*)d_ws;                          // 73,728 B
    __half* W0L = (__half*)((char*)d_ws + 73728);         // 36,864 B
    _Float16* xh = (_Float16*)((char*)d_ws + 110592);     // 8,388,608 B

    k_prep<<<2264, 256, 0, stream>>>(x, w_dcn, w_off, W2L, W0L, xh);
    k_fused<<<1024, 128, 0, stream>>>(x, xh, (const _Float16*)W2L,
                                      (const _Float16*)W0L, b_off, b_dcn, out);
}